// Round 7
// baseline (571.765 us; speedup 1.0000x reference)
//
#include <hip/hip_runtime.h>

// x: (B=2, C=128, H=256, W=256); WS=8, NH=16, d=8
#define BB 2
#define CC 128
#define HWSZ 65536
#define RSQE 0.9999950000374997f   // 1/sqrt(1+1e-5)
#define ATT_SCALE 0.35355339059327373f

typedef unsigned short u16;
using short8 = __attribute__((ext_vector_type(8))) short;
using f32x4  = __attribute__((ext_vector_type(4))) float;

#if defined(__has_builtin)
# if __has_builtin(__builtin_amdgcn_fdot2_f32_bf16)
#  define HAVE_DOT2 1
# endif
#endif

__device__ __forceinline__ float b2f(u16 u){
  return __uint_as_float(((unsigned int)u) << 16);
}
__device__ __forceinline__ u16 f2b(float f){
  unsigned int v = __float_as_uint(f);
  unsigned int r = (v + 0x7FFFu + ((v >> 16) & 1u)) >> 16;
  return (u16)r;
}

// tap offsets for the fused 13-tap 5x5 kernel (order matches k_prep_K)
__device__ const int c_DI[13] = {-2,-1,-1,-1, 0, 0,0,0,0, 1,1,1, 2};
__device__ const int c_DJ[13] = { 0,-1, 0, 1,-2,-1,0,1,2,-1,0,1, 0};

// ---------------- dtype detection ----------------
__global__ void k_detect(const u16* __restrict__ xr, int* __restrict__ flag){
  __shared__ int ws_[4];
  int tid = threadIdx.x;
  int cnt = 0;
  for (int i = 0; i < 16; ++i){
    u16 u = xr[tid*16 + i];
    int e = (u >> 7) & 0xFF;
    cnt += (e < 100 || e > 141) ? 1 : 0;
  }
  #pragma unroll
  for (int off = 32; off > 0; off >>= 1) cnt += __shfl_down(cnt, off, 64);
  if ((tid & 63) == 0) ws_[tid >> 6] = cnt;
  __syncthreads();
  if (tid == 0) *flag = (ws_[0]+ws_[1]+ws_[2]+ws_[3] > 64) ? 1 : 0;
}

// ---------------- ingest ----------------
__global__ void k_ingest4(const void* __restrict__ src, u16* __restrict__ dst,
                          int n4, const int* __restrict__ flag){
  int i = blockIdx.x * 256 + threadIdx.x;
  if (i >= n4) return;
  if (*flag){
    float4 f = ((const float4*)src)[i];
    ushort4 r; r.x=f2b(f.x); r.y=f2b(f.y); r.z=f2b(f.z); r.w=f2b(f.w);
    ((ushort4*)dst)[i] = r;
  } else {
    ((ushort4*)dst)[i] = ((const ushort4*)src)[i];
  }
}

struct PtrL { const void* p[19]; };

__global__ void k_ingest_w(PtrL pl, u16* __restrict__ dst, const int* __restrict__ flag){
  const int ends[19] = {16384,32768,49152,65536,212992,213120,213248,229632,229760,
                        229888,377344,459264,459392,508544,512144,520336,520464,520592,536976};
  int g = blockIdx.x * 256 + threadIdx.x;
  int idx = g * 4;
  if (idx >= 536976) return;
  int seg = 0, start = 0;
  #pragma unroll
  for (int s = 0; s < 19; ++s){ if (idx >= ends[s]){ seg = s+1; start = ends[s]; } }
  int local = idx - start;
  const void* sp = pl.p[seg];
  if (*flag){
    float4 f = ((const float4*)sp)[local >> 2];
    ushort4 r; r.x=f2b(f.x); r.y=f2b(f.y); r.z=f2b(f.z); r.w=f2b(f.w);
    *(ushort4*)(dst + idx) = r;
  } else {
    *(ushort4*)(dst + idx) = ((const ushort4*)sp)[local >> 2];
  }
}

// ---------------- precompute: channel-attention matrices + combined bias ----------------
__global__ void k_prep_A(const u16* __restrict__ fh, const u16* __restrict__ h1,
                         const u16* __restrict__ fw, const u16* __restrict__ w1,
                         const u16* __restrict__ l1b, const u16* __restrict__ l2b,
                         const u16* __restrict__ fcb,
                         float* __restrict__ A_h, float* __restrict__ A_w,
                         float* __restrict__ biasK){
  int idx = blockIdx.x * 256 + threadIdx.x;
  int o = idx >> 7, c = idx & 127;
  float ah = 0.f, aw = 0.f;
  for (int m = 0; m < 128; ++m){
    ah += b2f(fh[o*128 + m]) * b2f(h1[m*128 + c]);
    aw += b2f(fw[o*128 + m]) * b2f(w1[m*128 + c]);
  }
  A_h[idx] = ah; A_w[idx] = aw;
  if (c == 0) biasK[o] = b2f(l1b[o]) + b2f(l2b[o]) + b2f(fcb[o]);
}

// ---------------- precompute: rel table head-major f32 [16][225] ----------------
__global__ void k_prep_rel(const u16* __restrict__ rel, float* __restrict__ relo){
  int idx = blockIdx.x * 256 + threadIdx.x;
  if (idx >= 3600) return;
  int head = idx / 225, i = idx - head*225;
  relo[idx] = b2f(rel[i*16 + head]);
}

// ---------------- precompute: fused 13-tap kernel in bf16 [t][oc][ic] ----------------
__global__ void k_prep_K(const u16* __restrict__ hge_w, const u16* __restrict__ fc_w,
                         const u16* __restrict__ l1_w, const u16* __restrict__ l1_g,
                         const u16* __restrict__ l2_w, const u16* __restrict__ l2_g,
                         u16* __restrict__ Kwb){
  int idx = blockIdx.x * 256 + threadIdx.x;      // 16384, idx = o*128 + c
  int o = idx >> 7, c = idx & 127;
  float m0=0.f, m45=0.f, m90=0.f, m135=0.f, mgl=0.f;
  const u16* fo = fc_w + o*640;
  for (int m = 0; m < 128; ++m){
    const u16* hw9 = hge_w + (size_t)(m*128 + c)*9;
    m0   += b2f(fo[m      ]) * b2f(hw9[0]);
    m45  += b2f(fo[128 + m]) * b2f(hw9[1]);
    m90  += b2f(fo[256 + m]) * b2f(hw9[2]);
    m135 += b2f(fo[384 + m]) * b2f(hw9[3]);
    mgl  += b2f(fo[512 + m]) * b2f(hw9[8]);
  }
  float g1 = b2f(l1_g[o]) * RSQE;
  float g2 = b2f(l2_g[o]) * RSQE;
  float l1v[9];
  #pragma unroll
  for (int t = 0; t < 9; ++t) l1v[t] = b2f(l1_w[(size_t)idx*9 + t]) * g1;
  float l2v = b2f(l2_w[idx]) * g2;
  float kp[13];
  kp[0]  = -0.25f*mgl;
  kp[1]  =  m0 + 2.f*m45 + m90              - 0.25f*mgl + l1v[0];
  kp[2]  =  2.f*m0 + m45 - m135             - 0.50f*mgl + l1v[1];
  kp[3]  =  m0 - m90 - 2.f*m135             - 0.25f*mgl + l1v[2];
  kp[4]  = -0.25f*mgl;
  kp[5]  =  m45 + 2.f*m90 + m135            - 0.50f*mgl + l1v[3];
  kp[6]  =  4.f*mgl + l1v[4] + l2v;
  kp[7]  = -m45 - 2.f*m90 - m135            - 0.50f*mgl + l1v[5];
  kp[8]  = -0.25f*mgl;
  kp[9]  = -m0 + m90 + 2.f*m135             - 0.25f*mgl + l1v[6];
  kp[10] = -2.f*m0 - m45 + m135             - 0.50f*mgl + l1v[7];
  kp[11] = -m0 - 2.f*m45 - m90              - 0.25f*mgl + l1v[8];
  kp[12] = -0.25f*mgl;
  #pragma unroll
  for (int t = 0; t < 13; ++t) Kwb[t*16384 + idx] = f2b(kp[t]);
}

// ---------------- row/col means of x (canonical, pre-scale) ----------------
__global__ void k_means(const u16* __restrict__ x, float* __restrict__ mh, float* __restrict__ mw){
  __shared__ float colpart[4][256];
  int c = blockIdx.x, b = blockIdx.y;
  const u16* xp = x + (size_t)(b*CC + c)*HWSZ;
  int tid = threadIdx.x, lane = tid & 63, wv = tid >> 6;
  float c0=0.f,c1=0.f,c2=0.f,c3=0.f;
  for (int r = 0; r < 64; ++r){
    int h = wv*64 + r;
    ushort4 u = *(const ushort4*)(xp + h*256 + lane*4);
    float v0=b2f(u.x), v1=b2f(u.y), v2=b2f(u.z), v3=b2f(u.w);
    c0+=v0; c1+=v1; c2+=v2; c3+=v3;
    float rs = v0+v1+v2+v3;
    #pragma unroll
    for (int off = 32; off > 0; off >>= 1) rs += __shfl_down(rs, off, 64);
    if (lane == 0) mh[(size_t)(b*CC + c)*256 + h] = rs * (1.0f/256.0f);
  }
  colpart[wv][lane*4+0]=c0; colpart[wv][lane*4+1]=c1;
  colpart[wv][lane*4+2]=c2; colpart[wv][lane*4+3]=c3;
  __syncthreads();
  mw[(size_t)(b*CC + c)*256 + tid] =
    (colpart[0][tid]+colpart[1][tid]+colpart[2][tid]+colpart[3][tid]) * (1.0f/256.0f);
}

// ---------------- sigmoid(A @ mean) ----------------
__global__ void k_sig(const float* __restrict__ A_h, const float* __restrict__ A_w,
                      const float* __restrict__ mh, const float* __restrict__ mw,
                      float* __restrict__ s_h, float* __restrict__ s_w){
  int o = blockIdx.x, b = blockIdx.y, sel = blockIdx.z, t = threadIdx.x;
  const float* A = sel ? A_w : A_h;
  const float* m = sel ? mw : mh;
  float* s = sel ? s_w : s_h;
  float acc = 0.f;
  for (int c = 0; c < 128; ++c)
    acc += A[o*128 + c] * m[(size_t)(b*CC + c)*256 + t];
  s[(size_t)(b*CC + o)*256 + t] = 1.0f / (1.0f + __expf(-acc));
}

// ---------------- fused scale + CF->CL: xcl[b][h][w][c] = x*s_h*s_w ----------------
__global__ void k_scale2cl(const u16* __restrict__ cx, const float* __restrict__ s_h,
                           const float* __restrict__ s_w, u16* __restrict__ xcl){
  __shared__ u16 t[16][136];
  int b = blockIdx.z >> 8, h = blockIdx.z & 255;
  int w0 = blockIdx.x * 16;
  int tid = threadIdx.x;
  int ic = tid >> 1, wseg = (tid & 1) * 8;
  uint4 v = *(const uint4*)(cx + (size_t)(b*CC + ic)*HWSZ + h*256 + w0 + wseg);
  float sh = s_h[(size_t)(b*CC + ic)*256 + h];
  const float* swp = s_w + (size_t)(b*CC + ic)*256 + w0 + wseg;
  float4 swa = *(const float4*)swp;
  float4 swb = *(const float4*)(swp + 4);
  u16 tmp[8]; *(uint4*)tmp = v;
  t[wseg+0][ic] = f2b(b2f(tmp[0])*sh*swa.x);
  t[wseg+1][ic] = f2b(b2f(tmp[1])*sh*swa.y);
  t[wseg+2][ic] = f2b(b2f(tmp[2])*sh*swa.z);
  t[wseg+3][ic] = f2b(b2f(tmp[3])*sh*swa.w);
  t[wseg+4][ic] = f2b(b2f(tmp[4])*sh*swb.x);
  t[wseg+5][ic] = f2b(b2f(tmp[5])*sh*swb.y);
  t[wseg+6][ic] = f2b(b2f(tmp[6])*sh*swb.z);
  t[wseg+7][ic] = f2b(b2f(tmp[7])*sh*swb.w);
  __syncthreads();
  int w = tid >> 4, part = (tid & 15) * 8;
  uint4 o = *(const uint4*)&t[w][part];
  *(uint4*)(xcl + ((size_t)(b*256 + h)*256 + (w0 + w))*128 + part) = o;
}

// ---------------- plain CF -> CL transpose ----------------
__global__ void k_cf2cl(const u16* __restrict__ src, u16* __restrict__ dst){
  __shared__ u16 t[16][136];
  int b = blockIdx.z >> 8, h = blockIdx.z & 255;
  int w0 = blockIdx.x * 16;
  int tid = threadIdx.x;
  int ic = tid >> 1, wseg = (tid & 1) * 8;
  uint4 v = *(const uint4*)(src + (size_t)(b*CC + ic)*HWSZ + h*256 + w0 + wseg);
  u16 tmp[8]; *(uint4*)tmp = v;
  #pragma unroll
  for (int k = 0; k < 8; ++k) t[wseg + k][ic] = tmp[k];
  __syncthreads();
  int w = tid >> 4, part = (tid & 15) * 8;
  uint4 o = *(const uint4*)&t[w][part];
  *(uint4*)(dst + ((size_t)(b*256 + h)*256 + (w0 + w))*128 + part) = o;
}

// ---------------- MFMA implicit-GEMM conv, per-tap full-channel staging ----------------
// 13 phases; per phase: stage A(128px x 128ch shifted) + B(tap weights) into LDS,
// one barrier pair, 64 MFMA (4 kc-slices). 26 barriers vs conv5m's 104.
// XCD-chunked swizzle retained. Layout identical to proven k_mgemm.
__launch_bounds__(256)
__global__ void k_conv5t(const u16* __restrict__ xcl, const u16* __restrict__ Kwb,
                         const float* __restrict__ biasK, u16* __restrict__ outp){
  __shared__ u16 As[128][136];
  __shared__ u16 Bs[128][136];
  int tid = threadIdx.x;
  int wv = tid >> 6, lane = tid & 63;
  int q = lane >> 4, l16 = lane & 15;
  int pt0 = blockIdx.x;
  int pt = (pt0 & 7) * 128 + (pt0 >> 3);   // XCD-chunked swizzle (1024 % 8 == 0)
  int b = pt >> 9, h = (pt >> 1) & 255, w0 = (pt & 1) << 7;
  int mrow = (wv & 1) << 6, nrow = (wv >> 1) << 6;
  const u16* xb_b = xcl + (size_t)b*HWSZ*128;
  f32x4 acc[4][4];
  #pragma unroll
  for (int mt = 0; mt < 4; ++mt)
    #pragma unroll
    for (int nt = 0; nt < 4; ++nt) acc[mt][nt] = (f32x4){0.f,0.f,0.f,0.f};

  for (int t = 0; t < 13; ++t){
    int di = c_DI[t], dj = c_DJ[t];
    int hh2 = h + di;
    bool rowok = (unsigned)hh2 < 256u;
    const u16* rowbase = xb_b + (size_t)(rowok ? hh2 : 0)*256*128;
    const u16* Bb = Kwb + t*16384;
    __syncthreads();                 // prior phase's LDS reads complete
    #pragma unroll
    for (int i = 0; i < 8; ++i){
      int seg = i*256 + tid;
      int px = seg >> 4, chunk = (seg & 15) << 3;
      int col = w0 + dj + px;
      uint4 v = {0,0,0,0};
      if (rowok && (unsigned)col < 256u)
        v = *(const uint4*)(rowbase + col*128 + chunk);
      *(uint4*)&As[px][chunk] = v;
      *(uint4*)&Bs[px][chunk] = *(const uint4*)(Bb + seg*8);
    }
    __syncthreads();
    #pragma unroll
    for (int kc = 0; kc < 4; ++kc){
      short8 af[4], bf[4];
      #pragma unroll
      for (int mt = 0; mt < 4; ++mt) af[mt] = *(const short8*)&As[mrow + mt*16 + l16][kc*32 + q*8];
      #pragma unroll
      for (int nt = 0; nt < 4; ++nt) bf[nt] = *(const short8*)&Bs[nrow + nt*16 + l16][kc*32 + q*8];
      #pragma unroll
      for (int mt = 0; mt < 4; ++mt)
        #pragma unroll
        for (int nt = 0; nt < 4; ++nt)
          acc[mt][nt] = __builtin_amdgcn_mfma_f32_16x16x32_bf16(af[mt], bf[nt], acc[mt][nt], 0, 0, 0);
    }
  }
  #pragma unroll
  for (int nt = 0; nt < 4; ++nt){
    int n = nrow + nt*16 + l16;
    float bv = biasK[n];
    size_t cbase = (size_t)(b*CC + n)*HWSZ + h*256 + w0;
    #pragma unroll
    for (int mt = 0; mt < 4; ++mt){
      int m = mrow + mt*16 + q*4;
      ushort4 st;
      st.x = f2b(acc[mt][nt][0] + bv);
      st.y = f2b(acc[mt][nt][1] + bv);
      st.z = f2b(acc[mt][nt][2] + bv);
      st.w = f2b(acc[mt][nt][3] + bv);
      *(ushort4*)(outp + cbase + m) = st;
    }
  }
}

// ---------------- MFMA 1x1 GEMM: out[px][oc] = X_cl[px][:]·W[oc][:] ----------------
// mode 0: window layout [b][hh][ww][sel][head][pos][d] (qkv, nsel=3)
// mode 1: plane CF [b][oc][HW]; f32 if (Yf && *flag)   (proj_pw, nsel=1)
__launch_bounds__(256)
__global__ void k_mgemm(const u16* __restrict__ Xcl, const u16* __restrict__ W,
                        u16* __restrict__ Y, float* __restrict__ Yf,
                        const int* __restrict__ flag, int nsel, int mode){
  __shared__ u16 As[128][136];
  __shared__ u16 Bs[128][136];   // reused as Cs[m][n] in mode-0 epilogue
  int tid = threadIdx.x;
  int wv = tid >> 6, lane = tid & 63;
  int q = lane >> 4, l16 = lane & 15;
  int pt = blockIdx.x;
  int b = pt >> 9, h = (pt >> 1) & 255, w0 = (pt & 1) << 7;
  int mrow = (wv & 1) << 6, nrow = (wv >> 1) << 6;
  const u16* Abase = Xcl + ((size_t)(b*256 + h)*256 + w0)*128;
  #pragma unroll
  for (int i = 0; i < 8; ++i){
    int seg = i*256 + tid;
    *(uint4*)&As[seg >> 4][(seg & 15) << 3] = *(const uint4*)(Abase + seg*8);
  }
  for (int sel = 0; sel < nsel; ++sel){
    __syncthreads();                  // Bs/Cs free of previous readers
    const u16* Wb = W + sel*16384;
    #pragma unroll
    for (int i = 0; i < 8; ++i){
      int seg = i*256 + tid;
      *(uint4*)&Bs[seg >> 4][(seg & 15) << 3] = *(const uint4*)(Wb + seg*8);
    }
    __syncthreads();
    f32x4 acc[4][4];
    #pragma unroll
    for (int mt = 0; mt < 4; ++mt)
      #pragma unroll
      for (int nt = 0; nt < 4; ++nt) acc[mt][nt] = (f32x4){0.f,0.f,0.f,0.f};
    #pragma unroll
    for (int kc = 0; kc < 4; ++kc){
      short8 af[4], bf[4];
      #pragma unroll
      for (int mt = 0; mt < 4; ++mt) af[mt] = *(const short8*)&As[mrow + mt*16 + l16][kc*32 + q*8];
      #pragma unroll
      for (int nt = 0; nt < 4; ++nt) bf[nt] = *(const short8*)&Bs[nrow + nt*16 + l16][kc*32 + q*8];
      #pragma unroll
      for (int mt = 0; mt < 4; ++mt)
        #pragma unroll
        for (int nt = 0; nt < 4; ++nt)
          acc[mt][nt] = __builtin_amdgcn_mfma_f32_16x16x32_bf16(af[mt], bf[nt], acc[mt][nt], 0, 0, 0);
    }
    if (mode == 0){
      __syncthreads();                // all waves done with Bs
      #pragma unroll
      for (int mt = 0; mt < 4; ++mt){
        int m0i = mrow + mt*16 + q*4;
        #pragma unroll
        for (int nt = 0; nt < 4; ++nt){
          int n = nrow + nt*16 + l16;
          Bs[m0i+0][n] = f2b(acc[mt][nt][0]);
          Bs[m0i+1][n] = f2b(acc[mt][nt][1]);
          Bs[m0i+2][n] = f2b(acc[mt][nt][2]);
          Bs[m0i+3][n] = f2b(acc[mt][nt][3]);
        }
      }
      __syncthreads();
      int win = tid >> 4, head = tid & 15;
      size_t obase = (((((size_t)b*32 + (h >> 3))*32 + (w0 >> 3) + win)*3 + sel)*16 + head)*512
                     + (size_t)(h & 7)*64;
      #pragma unroll
      for (int pj = 0; pj < 8; ++pj){
        uint4 vv = *(const uint4*)&Bs[win*8 + pj][head*8];
        *(uint4*)(Y + obase + pj*8) = vv;
      }
    } else {
      int f32o = (Yf != nullptr) && (*flag != 0);
      #pragma unroll
      for (int nt = 0; nt < 4; ++nt){
        int n = nrow + nt*16 + l16;
        size_t cbase = (size_t)(b*CC + n)*HWSZ + h*256 + w0;
        #pragma unroll
        for (int mt = 0; mt < 4; ++mt){
          int m = mrow + mt*16 + q*4;
          if (f32o){
            float4 st; st.x=acc[mt][nt][0]; st.y=acc[mt][nt][1];
            st.z=acc[mt][nt][2]; st.w=acc[mt][nt][3];
            *(float4*)(Yf + cbase + m) = st;
          } else {
            ushort4 st;
            st.x = f2b(acc[mt][nt][0]); st.y = f2b(acc[mt][nt][1]);
            st.z = f2b(acc[mt][nt][2]); st.w = f2b(acc[mt][nt][3]);
            *(ushort4*)(Y + cbase + m) = st;
          }
        }
      }
    }
  }
}

// ---------------- windowed attention v3: one wave per (window, head) ----------------
// qkvw layout: [b][hh][ww][sel(3)][head(16)][pos(64)][d(8)] bf16
// grid: (8 window-groups, 32 hh, b*16+head); block 256 = 4 waves = 4 windows
__launch_bounds__(256)
__global__ void k_attn3(const u16* __restrict__ qkvw, const float* __restrict__ relo,
                        u16* __restrict__ obuf){
  __shared__ float relf[228];
  __shared__ u16  kls[4][64][8];
  __shared__ float vls[4][64][8];
  int tid = threadIdx.x, wv = tid >> 6, lane = tid & 63;
  int b = blockIdx.z >> 4, head = blockIdx.z & 15;
  int hh = blockIdx.y, ww = blockIdx.x * 4 + wv;

  for (int e = tid; e < 225; e += 256) relf[e] = relo[head*225 + e];

  size_t base = (((size_t)b*32 + hh)*32 + ww)*3*8192 + (size_t)head*512;
  uint4 qv = *(const uint4*)(qkvw + base + lane*8);
  *(uint4*)&kls[wv][lane][0] = *(const uint4*)(qkvw + base + 8192 + lane*8);
  {
    uint4 raw = *(const uint4*)(qkvw + base + 16384 + lane*8);
    u16 tv[8]; *(uint4*)tv = raw;
    float4 lo, hi;
    lo.x=b2f(tv[0]); lo.y=b2f(tv[1]); lo.z=b2f(tv[2]); lo.w=b2f(tv[3]);
    hi.x=b2f(tv[4]); hi.y=b2f(tv[5]); hi.z=b2f(tv[6]); hi.w=b2f(tv[7]);
    *(float4*)&vls[wv][lane][0] = lo;
    *(float4*)&vls[wv][lane][4] = hi;
  }
  __syncthreads();     // relf visibility across waves (K/V slices are same-wave)

  int qi = lane >> 3, qj = lane & 7;
  const float* rbase = relf + (qi + 7)*15 + (qj + 7);
  float s[64];
#if HAVE_DOT2
  typedef __bf16 bf2 __attribute__((ext_vector_type(2)));
  bf2 q0 = __builtin_bit_cast(bf2, qv.x), q1 = __builtin_bit_cast(bf2, qv.y);
  bf2 q2 = __builtin_bit_cast(bf2, qv.z), q3 = __builtin_bit_cast(bf2, qv.w);
  #pragma unroll
  for (int kp = 0; kp < 64; ++kp){
    uint4 kv = *(const uint4*)&kls[wv][kp][0];
    float d = __builtin_amdgcn_fdot2_f32_bf16(q3, __builtin_bit_cast(bf2, kv.w), 0.f, false);
    d = __builtin_amdgcn_fdot2_f32_bf16(q2, __builtin_bit_cast(bf2, kv.z), d, false);
    d = __builtin_amdgcn_fdot2_f32_bf16(q1, __builtin_bit_cast(bf2, kv.y), d, false);
    d = __builtin_amdgcn_fdot2_f32_bf16(q0, __builtin_bit_cast(bf2, kv.x), d, false);
    s[kp] = fmaf(d, ATT_SCALE, rbase[-((kp>>3)*15 + (kp&7))]);
  }
#else
  float qf[8];
  { u16 tq[8]; *(uint4*)tq = qv;
    #pragma unroll
    for (int d = 0; d < 8; ++d) qf[d] = b2f(tq[d]); }
  #pragma unroll
  for (int kp = 0; kp < 64; ++kp){
    uint4 kv = *(const uint4*)&kls[wv][kp][0];
    u16 tk[8]; *(uint4*)tk = kv;
    float d = 0.f;
    #pragma unroll
    for (int dd = 0; dd < 8; ++dd) d = fmaf(qf[dd], b2f(tk[dd]), d);
    s[kp] = fmaf(d, ATT_SCALE, rbase[-((kp>>3)*15 + (kp&7))]);
  }
#endif
  float t16[16];
  #pragma unroll
  for (int i = 0; i < 16; ++i)
    t16[i] = fmaxf(fmaxf(s[i], s[i+16]), fmaxf(s[i+32], s[i+48]));
  float mx = t16[0];
  #pragma unroll
  for (int i = 1; i < 16; ++i) mx = fmaxf(mx, t16[i]);
  #pragma unroll
  for (int kp = 0; kp < 64; ++kp) s[kp] = __expf(s[kp] - mx);
  #pragma unroll
  for (int i = 0; i < 16; ++i)
    t16[i] = (s[i] + s[i+16]) + (s[i+32] + s[i+48]);
  float sum = t16[0];
  #pragma unroll
  for (int i = 1; i < 16; ++i) sum += t16[i];
  float inv = 1.0f / sum;
  float ov[8] = {0.f,0.f,0.f,0.f,0.f,0.f,0.f,0.f};
  #pragma unroll
  for (int kp = 0; kp < 64; ++kp){
    float4 va = *(const float4*)&vls[wv][kp][0];
    float4 vb = *(const float4*)&vls[wv][kp][4];
    float pp = s[kp];
    ov[0] = fmaf(pp, va.x, ov[0]); ov[1] = fmaf(pp, va.y, ov[1]);
    ov[2] = fmaf(pp, va.z, ov[2]); ov[3] = fmaf(pp, va.w, ov[3]);
    ov[4] = fmaf(pp, vb.x, ov[4]); ov[5] = fmaf(pp, vb.y, ov[5]);
    ov[6] = fmaf(pp, vb.z, ov[6]); ov[7] = fmaf(pp, vb.w, ov[7]);
  }
  size_t obase = (size_t)(b*CC + head*8)*HWSZ + (size_t)(hh*8 + qi)*256 + ww*8 + qj;
  #pragma unroll
  for (int d = 0; d < 8; ++d)
    obuf[obase + (size_t)d*HWSZ] = f2b(ov[d] * inv);
}

// ---------------- u = avgpool_x(o) + avgpool_y(o) + local (LDS-tiled) ----------------
// 64x64 output tile per block; halo tile 71 rows x 80 cols (cols w0-8 .. w0+71)
__launch_bounds__(256)
__global__ void k_pool2(const u16* __restrict__ obuf, u16* __restrict__ localb){
  __shared__ u16 t[71][88];       // row pad to 88 u16 (176B) keeps uint4 alignment
  int bc = blockIdx.z;
  int h0 = blockIdx.y * 64, w0 = blockIdx.x * 64;
  int tid = threadIdx.x;
  const u16* op = obuf + (size_t)bc * HWSZ;

  // load 71 rows x 10 ushort8-chunks: rows h0-3..h0+67, cols w0-8..w0+71
  for (int e = tid; e < 710; e += 256){
    int tr = e / 10, ci = e - tr*10;
    int gt = h0 - 3 + tr;
    if (gt == 256) gt = 254;               // reflect pad row
    bool rv = (unsigned)gt <= 255u;        // else zero (reduce_window pad)
    int g0 = w0 - 8 + ci*8;
    uint4 v = {0,0,0,0};
    if (rv){
      if (g0 >= 0 && g0 <= 248){
        v = *(const uint4*)(op + gt*256 + g0);
      } else {
        u16 tmp[8];
        #pragma unroll
        for (int j = 0; j < 8; ++j){
          int g = g0 + j;
          if (g == 256) g = 254;           // reflect pad col
          tmp[j] = ((unsigned)g <= 255u) ? op[gt*256 + g] : (u16)0;
        }
        v = *(const uint4*)tmp;
      }
    }
    *(uint4*)&t[tr][ci*8] = v;
  }
  __syncthreads();

  int ty = tid >> 4, tx = tid & 15;
  int r0 = ty*4, c0 = tx*4;                // 4x4 outputs per thread
  // vertical 8-tap sums via sliding window: sxv[r][c] = sum_{i=0..7} t[r0+r+i][c0+8+c]
  float sxv[4][4];
  #pragma unroll
  for (int c = 0; c < 4; ++c){
    float col[11];
    #pragma unroll
    for (int i = 0; i < 11; ++i) col[i] = b2f(t[r0+i][c0+8+c]);
    float s = ((col[0]+col[1])+(col[2]+col[3]))+((col[4]+col[5])+(col[6]+col[7]));
    sxv[0][c] = s;
    s += col[8]  - col[0]; sxv[1][c] = s;
    s += col[9]  - col[1]; sxv[2][c] = s;
    s += col[10] - col[2]; sxv[3][c] = s;
  }
  #pragma unroll
  for (int r = 0; r < 4; ++r){
    int rr = r0 + r;
    // horizontal 8-tap sums: sy[c] = sum_{j=0..7} t[rr+3][c0+5+c+j]
    float pre[11];
    #pragma unroll
    for (int j = 0; j < 11; ++j) pre[j] = b2f(t[rr+3][c0+5+j]);
    float sy0 = ((pre[0]+pre[1])+(pre[2]+pre[3]))+((pre[4]+pre[5])+(pre[6]+pre[7]));
    float sy1 = sy0 + pre[8]  - pre[0];
    float sy2 = sy1 + pre[9]  - pre[1];
    float sy3 = sy2 + pre[10] - pre[2];
    size_t base = (size_t)bc*HWSZ + (size_t)(h0+rr)*256 + (w0+c0);
    ushort4 lv = *(const ushort4*)(localb + base);
    ushort4 st;
    st.x = f2b((sxv[r][0]+sy0)*0.125f + b2f(lv.x));
    st.y = f2b((sxv[r][1]+sy1)*0.125f + b2f(lv.y));
    st.z = f2b((sxv[r][2]+sy2)*0.125f + b2f(lv.z));
    st.w = f2b((sxv[r][3]+sy3)*0.125f + b2f(lv.w));
    *(ushort4*)(localb + base) = st;
  }
}

// ---------------- depthwise 8x8 conv + bn (CF in, CF out), LDS-tiled ----------------
// 64x128 output tile per block; halo 71 rows x 144 cols bf16 in LDS.
// Each thread: 4 rows x 8 cols outputs; 11 tap rows shared; fdot2 bf16 inner product.
__launch_bounds__(256)
__global__ void k_dw2(const u16* __restrict__ u_, const u16* __restrict__ dww,
                      const u16* __restrict__ g, const u16* __restrict__ bta,
                      u16* __restrict__ dwout){
  __shared__ u16 xt[71][152];     // row stride 304 B (16B-aligned)
  int c = blockIdx.z & 127, b = blockIdx.z >> 7;
  int h0 = blockIdx.y * 64, w0 = blockIdx.x * 128;
  int tid = threadIdx.x;
  const u16* up = u_ + (size_t)(b*CC + c)*HWSZ;

  // halo: LDS row tr -> global row h0-3+tr; LDS col l -> global col w0-8+l (l<144)
  for (int e = tid; e < 71*18; e += 256){
    int tr = e / 18, ci = e - tr*18;
    int gt = h0 - 3 + tr;
    if (gt == 256) gt = 254;               // reflect row (pad-1 frame)
    int g0 = w0 - 8 + ci*8;
    uint4 v = {0,0,0,0};
    if ((unsigned)gt <= 255u){
      if (g0 >= 0 && g0 <= 248){
        v = *(const uint4*)(up + gt*256 + g0);
      } else {
        u16 tmp[8];
        #pragma unroll
        for (int j = 0; j < 8; ++j){
          int gw = g0 + j;
          if (gw == 256) gw = 254;         // reflect col
          tmp[j] = ((unsigned)gw <= 255u) ? up[gt*256 + gw] : (u16)0;
        }
        v = *(const uint4*)tmp;
      }
    }
    *(uint4*)&xt[tr][ci*8] = v;
  }

#if HAVE_DOT2
  typedef __bf16 bf2v __attribute__((ext_vector_type(2)));
  // weights as raw bf16 pairs: wp[wr*4+p] = (w[wr][2p], w[wr][2p+1])
  unsigned int wp[32];
  {
    const uint4* wsrc = (const uint4*)(dww + c*64);
    #pragma unroll
    for (int t = 0; t < 8; ++t){
      uint4 v = wsrc[t];
      wp[t*4+0]=v.x; wp[t*4+1]=v.y; wp[t*4+2]=v.z; wp[t*4+3]=v.w;
    }
  }
#else
  float wf[64];
  {
    const u16* wsrc = dww + c*64;
    #pragma unroll
    for (int t = 0; t < 64; ++t) wf[t] = b2f(wsrc[t]);
  }
#endif
  __syncthreads();

  int tx = tid & 15, ty = tid >> 4;
  int r0 = ty*4;                  // tile-local output rows r0..r0+3
  int cb = tx*8;                  // output col c -> LDS col cb+8+k; taps cols cb+5+k+j
  float acc[4][8];
  #pragma unroll
  for (int r = 0; r < 4; ++r)
    #pragma unroll
    for (int k = 0; k < 8; ++k) acc[r][k] = 0.f;

  #pragma unroll
  for (int i = 0; i < 11; ++i){
    const u16* rowp = &xt[r0 + i][cb + 4];
    uint2 av = *(const uint2*)(rowp);       // cols +4..+7
    uint4 mv = *(const uint4*)(rowp + 4);   // cols +8..+15
    uint2 zv = *(const uint2*)(rowp + 12);  // cols +16..+19
    unsigned int d0=av.x, d1=av.y, d2=mv.x, d3=mv.y, d4=mv.z, d5=mv.w, d6=zv.x, d7=zv.y;
    unsigned int dd[8] = {d0,d1,d2,d3,d4,d5,d6,d7};
#if HAVE_DOT2
    // xp[t] = bf16 pair (col 4+t, col 5+t), t=1..14
    unsigned int xp[15];
    #pragma unroll
    for (int t = 1; t < 15; ++t)
      xp[t] = (t & 1) ? ((dd[t>>1] >> 16) | (dd[(t>>1)+1] << 16)) : dd[t>>1];
    #pragma unroll
    for (int dr = 0; dr < 4; ++dr){
      int wr = i - dr;
      if (wr >= 0 && wr < 8){
        #pragma unroll
        for (int k = 0; k < 8; ++k){
          float s = acc[dr][k];
          #pragma unroll
          for (int p = 0; p < 4; ++p)
            s = __builtin_amdgcn_fdot2_f32_bf16(
                  __builtin_bit_cast(bf2v, wp[wr*4+p]),
                  __builtin_bit_cast(bf2v, xp[1+k+2*p]), s, false);
          acc[dr][k] = s;
        }
      }
    }
#else
    float xw[16];
    #pragma unroll
    for (int t = 1; t < 16; ++t){
      unsigned int w32 = dd[t>>1];
      xw[t] = __uint_as_float((t & 1) ? (w32 & 0xFFFF0000u) : (w32 << 16));
    }
    #pragma unroll
    for (int dr = 0; dr < 4; ++dr){
      int wr = i - dr;
      if (wr >= 0 && wr < 8){
        #pragma unroll
        for (int k = 0; k < 8; ++k){
          float s = acc[dr][k];
          #pragma unroll
          for (int j = 0; j < 8; ++j)
            s = fmaf(wf[wr*8+j], xw[1+k+j], s);
          acc[dr][k] = s;
        }
      }
    }
#endif
  }

  float scale = b2f(g[c]) * RSQE;
  float bb = b2f(bta[c]);
  size_t obase = (size_t)(b*CC + c)*HWSZ + (size_t)(h0 + r0)*256 + w0 + cb;
  #pragma unroll
  for (int r = 0; r < 4; ++r){
    u16 po[8];
    #pragma unroll
    for (int k = 0; k < 8; ++k) po[k] = f2b(acc[r][k]*scale + bb);
    *(uint4*)(dwout + obase + (size_t)r*256) = *(uint4*)po;
  }
}

// ---------------- launcher ----------------
extern "C" void kernel_launch(void* const* d_in, const int* in_sizes, int n_in,
                              void* d_out, int out_size, void* d_ws, size_t ws_size,
                              hipStream_t stream) {
  char* p = (char*)d_ws;
  u16* cx     = (u16*)p; p += 33554432;   // canonical CF x -> attn output planes
  u16* xcl    = (u16*)p; p += 33554432;   // scaled CL x -> dw output CL
  u16* qkvb   = (u16*)p; p += 100663296;  // qkvw window layout -> dw output CF
  u16* cw     = (u16*)p; p += 1074176;
  float* A_h    = (float*)p; p += 65536;
  float* A_w    = (float*)p; p += 65536;
  u16*  Kwb     = (u16*)p;  p += 425984;
  float* biasK  = (float*)p; p += 1024;
  float* mh     = (float*)p; p += 262144;
  float* mw     = (float*)p; p += 262144;
  float* s_h    = (float*)p; p += 262144;
  float* s_w    = (float*)p; p += 262144;
  int* flag     = (int*)p;   p += 256;
  float* relo   = (float*)p; p += 16384;  // rel table head-major f32 [16][225]

  u16* localb = (u16*)d_out;     // d_out doubles as `local` scratch until final GEMM
  u16* qkvw   = qkvb;
  u16* obuf   = cx;              // attn output planes (cx dead after qkv gemm)
  u16* dwbuf  = qkvb;            // dw CF output (qkvw dead after attn)
  u16* dwcl   = xcl;             // dw CL output (xcl dead after qkv gemm)

  const int O_h1=0, O_w1=16384, O_fh=32768, O_fw=49152, O_l1w=65536, O_l1g=212992,
            O_l1b=213120, O_l2w=213248, O_l2g=229632, O_l2b=229760, O_hge=229888,
            O_fcw=377344, O_fcb=459264, O_qkvw=459392, O_rel=508544, O_dw=512144,
            O_pg=520336, O_pb=520464, O_pw=520592;

  k_detect<<<1, 256, 0, stream>>>((const u16*)d_in[0], flag);
  k_ingest4<<<16384, 256, 0, stream>>>(d_in[0], cx, 4194304, flag);
  PtrL pl;
  for (int i = 0; i < 19; ++i) pl.p[i] = d_in[i+1];
  k_ingest_w<<<525, 256, 0, stream>>>(pl, cw, flag);

  k_prep_A<<<64, 256, 0, stream>>>(cw+O_fh, cw+O_h1, cw+O_fw, cw+O_w1,
                                   cw+O_l1b, cw+O_l2b, cw+O_fcb, A_h, A_w, biasK);
  k_prep_rel<<<15, 256, 0, stream>>>(cw+O_rel, relo);
  k_prep_K<<<64, 256, 0, stream>>>(cw+O_hge, cw+O_fcw, cw+O_l1w, cw+O_l1g,
                                   cw+O_l2w, cw+O_l2g, Kwb);
  k_means<<<dim3(128, 2), 256, 0, stream>>>(cx, mh, mw);
  k_sig<<<dim3(128, 2, 2), 256, 0, stream>>>(A_h, A_w, mh, mw, s_h, s_w);
  k_scale2cl<<<dim3(16, 1, 512), 256, 0, stream>>>(cx, s_h, s_w, xcl);

  k_conv5t<<<1024, 256, 0, stream>>>(xcl, Kwb, biasK, localb);
  k_mgemm<<<1024, 256, 0, stream>>>(xcl, cw+O_qkvw, qkvw, nullptr, flag, 3, 0);
  k_attn3<<<dim3(8, 32, 32), 256, 0, stream>>>(qkvw, relo, obuf);
  k_pool2<<<dim3(4, 4, 256), 256, 0, stream>>>(obuf, localb);
  k_dw2<<<dim3(2, 4, 256), 256, 0, stream>>>(localb, cw+O_dw, cw+O_pg, cw+O_pb, dwbuf);
  k_cf2cl<<<dim3(16, 1, 512), 256, 0, stream>>>(dwbuf, dwcl);
  k_mgemm<<<1024, 256, 0, stream>>>(dwcl, cw+O_pw, (u16*)d_out, (float*)d_out, flag, 1, 1);
}

// Round 8
// 540.235 us; speedup vs baseline: 1.0584x; 1.0584x over previous
//
#include <hip/hip_runtime.h>

// x: (B=2, C=128, H=256, W=256); WS=8, NH=16, d=8
#define BB 2
#define CC 128
#define HWSZ 65536
#define RSQE 0.9999950000374997f   // 1/sqrt(1+1e-5)
#define ATT_SCALE 0.35355339059327373f

typedef unsigned short u16;
using short8 = __attribute__((ext_vector_type(8))) short;
using f32x4  = __attribute__((ext_vector_type(4))) float;

#if defined(__has_builtin)
# if __has_builtin(__builtin_amdgcn_fdot2_f32_bf16)
#  define HAVE_DOT2 1
# endif
#endif

__device__ __forceinline__ float b2f(u16 u){
  return __uint_as_float(((unsigned int)u) << 16);
}
__device__ __forceinline__ u16 f2b(float f){
  unsigned int v = __float_as_uint(f);
  unsigned int r = (v + 0x7FFFu + ((v >> 16) & 1u)) >> 16;
  return (u16)r;
}

// async global->LDS, 16B per lane; LDS dest = wave-uniform base + lane*16
__device__ __forceinline__ void gload16(const u16* g, u16* l){
  __builtin_amdgcn_global_load_lds(
      (__attribute__((address_space(1))) void*)(g),
      (__attribute__((address_space(3))) void*)(l), 16, 0, 0);
}

// tap offsets for the fused 13-tap 5x5 kernel (order matches k_prep_K)
__device__ const int c_DI[13] = {-2,-1,-1,-1, 0, 0,0,0,0, 1,1,1, 2};
__device__ const int c_DJ[13] = { 0,-1, 0, 1,-2,-1,0,1,2,-1,0,1, 0};

// ---------------- dtype detection ----------------
__global__ void k_detect(const u16* __restrict__ xr, int* __restrict__ flag){
  __shared__ int ws_[4];
  int tid = threadIdx.x;
  int cnt = 0;
  for (int i = 0; i < 16; ++i){
    u16 u = xr[tid*16 + i];
    int e = (u >> 7) & 0xFF;
    cnt += (e < 100 || e > 141) ? 1 : 0;
  }
  #pragma unroll
  for (int off = 32; off > 0; off >>= 1) cnt += __shfl_down(cnt, off, 64);
  if ((tid & 63) == 0) ws_[tid >> 6] = cnt;
  __syncthreads();
  if (tid == 0) *flag = (ws_[0]+ws_[1]+ws_[2]+ws_[3] > 64) ? 1 : 0;
}

// ---------------- zero page ----------------
__global__ void k_zero(uint4* zp){ zp[threadIdx.x] = (uint4){0,0,0,0}; }

// ---------------- ingest ----------------
__global__ void k_ingest4(const void* __restrict__ src, u16* __restrict__ dst,
                          int n4, const int* __restrict__ flag){
  int i = blockIdx.x * 256 + threadIdx.x;
  if (i >= n4) return;
  if (*flag){
    float4 f = ((const float4*)src)[i];
    ushort4 r; r.x=f2b(f.x); r.y=f2b(f.y); r.z=f2b(f.z); r.w=f2b(f.w);
    ((ushort4*)dst)[i] = r;
  } else {
    ((ushort4*)dst)[i] = ((const ushort4*)src)[i];
  }
}

struct PtrL { const void* p[19]; };

__global__ void k_ingest_w(PtrL pl, u16* __restrict__ dst, const int* __restrict__ flag){
  const int ends[19] = {16384,32768,49152,65536,212992,213120,213248,229632,229760,
                        229888,377344,459264,459392,508544,512144,520336,520464,520592,536976};
  int g = blockIdx.x * 256 + threadIdx.x;
  int idx = g * 4;
  if (idx >= 536976) return;
  int seg = 0, start = 0;
  #pragma unroll
  for (int s = 0; s < 19; ++s){ if (idx >= ends[s]){ seg = s+1; start = ends[s]; } }
  int local = idx - start;
  const void* sp = pl.p[seg];
  if (*flag){
    float4 f = ((const float4*)sp)[local >> 2];
    ushort4 r; r.x=f2b(f.x); r.y=f2b(f.y); r.z=f2b(f.z); r.w=f2b(f.w);
    *(ushort4*)(dst + idx) = r;
  } else {
    *(ushort4*)(dst + idx) = ((const ushort4*)sp)[local >> 2];
  }
}

// ---------------- precompute: channel-attention matrices + combined bias ----------------
__global__ void k_prep_A(const u16* __restrict__ fh, const u16* __restrict__ h1,
                         const u16* __restrict__ fw, const u16* __restrict__ w1,
                         const u16* __restrict__ l1b, const u16* __restrict__ l2b,
                         const u16* __restrict__ fcb,
                         float* __restrict__ A_h, float* __restrict__ A_w,
                         float* __restrict__ biasK){
  int idx = blockIdx.x * 256 + threadIdx.x;
  int o = idx >> 7, c = idx & 127;
  float ah = 0.f, aw = 0.f;
  for (int m = 0; m < 128; ++m){
    ah += b2f(fh[o*128 + m]) * b2f(h1[m*128 + c]);
    aw += b2f(fw[o*128 + m]) * b2f(w1[m*128 + c]);
  }
  A_h[idx] = ah; A_w[idx] = aw;
  if (c == 0) biasK[o] = b2f(l1b[o]) + b2f(l2b[o]) + b2f(fcb[o]);
}

// ---------------- precompute: rel table head-major f32 [16][225] ----------------
__global__ void k_prep_rel(const u16* __restrict__ rel, float* __restrict__ relo){
  int idx = blockIdx.x * 256 + threadIdx.x;
  if (idx >= 3600) return;
  int head = idx / 225, i = idx - head*225;
  relo[idx] = b2f(rel[i*16 + head]);
}

// ---------------- precompute: fused 13-tap kernel in bf16 [t][oc][ic] ----------------
__global__ void k_prep_K(const u16* __restrict__ hge_w, const u16* __restrict__ fc_w,
                         const u16* __restrict__ l1_w, const u16* __restrict__ l1_g,
                         const u16* __restrict__ l2_w, const u16* __restrict__ l2_g,
                         u16* __restrict__ Kwb){
  int idx = blockIdx.x * 256 + threadIdx.x;      // 16384, idx = o*128 + c
  int o = idx >> 7, c = idx & 127;
  float m0=0.f, m45=0.f, m90=0.f, m135=0.f, mgl=0.f;
  const u16* fo = fc_w + o*640;
  for (int m = 0; m < 128; ++m){
    const u16* hw9 = hge_w + (size_t)(m*128 + c)*9;
    m0   += b2f(fo[m      ]) * b2f(hw9[0]);
    m45  += b2f(fo[128 + m]) * b2f(hw9[1]);
    m90  += b2f(fo[256 + m]) * b2f(hw9[2]);
    m135 += b2f(fo[384 + m]) * b2f(hw9[3]);
    mgl  += b2f(fo[512 + m]) * b2f(hw9[8]);
  }
  float g1 = b2f(l1_g[o]) * RSQE;
  float g2 = b2f(l2_g[o]) * RSQE;
  float l1v[9];
  #pragma unroll
  for (int t = 0; t < 9; ++t) l1v[t] = b2f(l1_w[(size_t)idx*9 + t]) * g1;
  float l2v = b2f(l2_w[idx]) * g2;
  float kp[13];
  kp[0]  = -0.25f*mgl;
  kp[1]  =  m0 + 2.f*m45 + m90              - 0.25f*mgl + l1v[0];
  kp[2]  =  2.f*m0 + m45 - m135             - 0.50f*mgl + l1v[1];
  kp[3]  =  m0 - m90 - 2.f*m135             - 0.25f*mgl + l1v[2];
  kp[4]  = -0.25f*mgl;
  kp[5]  =  m45 + 2.f*m90 + m135            - 0.50f*mgl + l1v[3];
  kp[6]  =  4.f*mgl + l1v[4] + l2v;
  kp[7]  = -m45 - 2.f*m90 - m135            - 0.50f*mgl + l1v[5];
  kp[8]  = -0.25f*mgl;
  kp[9]  = -m0 + m90 + 2.f*m135             - 0.25f*mgl + l1v[6];
  kp[10] = -2.f*m0 - m45 + m135             - 0.50f*mgl + l1v[7];
  kp[11] = -m0 - 2.f*m45 - m90              - 0.25f*mgl + l1v[8];
  kp[12] = -0.25f*mgl;
  #pragma unroll
  for (int t = 0; t < 13; ++t) Kwb[t*16384 + idx] = f2b(kp[t]);
}

// ---------------- row/col means of x (canonical, pre-scale) ----------------
__global__ void k_means(const u16* __restrict__ x, float* __restrict__ mh, float* __restrict__ mw){
  __shared__ float colpart[4][256];
  int c = blockIdx.x, b = blockIdx.y;
  const u16* xp = x + (size_t)(b*CC + c)*HWSZ;
  int tid = threadIdx.x, lane = tid & 63, wv = tid >> 6;
  float c0=0.f,c1=0.f,c2=0.f,c3=0.f;
  for (int r = 0; r < 64; ++r){
    int h = wv*64 + r;
    ushort4 u = *(const ushort4*)(xp + h*256 + lane*4);
    float v0=b2f(u.x), v1=b2f(u.y), v2=b2f(u.z), v3=b2f(u.w);
    c0+=v0; c1+=v1; c2+=v2; c3+=v3;
    float rs = v0+v1+v2+v3;
    #pragma unroll
    for (int off = 32; off > 0; off >>= 1) rs += __shfl_down(rs, off, 64);
    if (lane == 0) mh[(size_t)(b*CC + c)*256 + h] = rs * (1.0f/256.0f);
  }
  colpart[wv][lane*4+0]=c0; colpart[wv][lane*4+1]=c1;
  colpart[wv][lane*4+2]=c2; colpart[wv][lane*4+3]=c3;
  __syncthreads();
  mw[(size_t)(b*CC + c)*256 + tid] =
    (colpart[0][tid]+colpart[1][tid]+colpart[2][tid]+colpart[3][tid]) * (1.0f/256.0f);
}

// ---------------- sigmoid(A @ mean) ----------------
__global__ void k_sig(const float* __restrict__ A_h, const float* __restrict__ A_w,
                      const float* __restrict__ mh, const float* __restrict__ mw,
                      float* __restrict__ s_h, float* __restrict__ s_w){
  int o = blockIdx.x, b = blockIdx.y, sel = blockIdx.z, t = threadIdx.x;
  const float* A = sel ? A_w : A_h;
  const float* m = sel ? mw : mh;
  float* s = sel ? s_w : s_h;
  float acc = 0.f;
  for (int c = 0; c < 128; ++c)
    acc += A[o*128 + c] * m[(size_t)(b*CC + c)*256 + t];
  s[(size_t)(b*CC + o)*256 + t] = 1.0f / (1.0f + __expf(-acc));
}

// ---------------- fused scale + CF->CL: xcl[b][h][w][c] = x*s_h*s_w ----------------
__global__ void k_scale2cl(const u16* __restrict__ cx, const float* __restrict__ s_h,
                           const float* __restrict__ s_w, u16* __restrict__ xcl){
  __shared__ u16 t[16][136];
  int b = blockIdx.z >> 8, h = blockIdx.z & 255;
  int w0 = blockIdx.x * 16;
  int tid = threadIdx.x;
  int ic = tid >> 1, wseg = (tid & 1) * 8;
  uint4 v = *(const uint4*)(cx + (size_t)(b*CC + ic)*HWSZ + h*256 + w0 + wseg);
  float sh = s_h[(size_t)(b*CC + ic)*256 + h];
  const float* swp = s_w + (size_t)(b*CC + ic)*256 + w0 + wseg;
  float4 swa = *(const float4*)swp;
  float4 swb = *(const float4*)(swp + 4);
  u16 tmp[8]; *(uint4*)tmp = v;
  t[wseg+0][ic] = f2b(b2f(tmp[0])*sh*swa.x);
  t[wseg+1][ic] = f2b(b2f(tmp[1])*sh*swa.y);
  t[wseg+2][ic] = f2b(b2f(tmp[2])*sh*swa.z);
  t[wseg+3][ic] = f2b(b2f(tmp[3])*sh*swa.w);
  t[wseg+4][ic] = f2b(b2f(tmp[4])*sh*swb.x);
  t[wseg+5][ic] = f2b(b2f(tmp[5])*sh*swb.y);
  t[wseg+6][ic] = f2b(b2f(tmp[6])*sh*swb.z);
  t[wseg+7][ic] = f2b(b2f(tmp[7])*sh*swb.w);
  __syncthreads();
  int w = tid >> 4, part = (tid & 15) * 8;
  uint4 o = *(const uint4*)&t[w][part];
  *(uint4*)(xcl + ((size_t)(b*256 + h)*256 + (w0 + w))*128 + part) = o;
}

// ---------------- plain CF -> CL transpose ----------------
__global__ void k_cf2cl(const u16* __restrict__ src, u16* __restrict__ dst){
  __shared__ u16 t[16][136];
  int b = blockIdx.z >> 8, h = blockIdx.z & 255;
  int w0 = blockIdx.x * 16;
  int tid = threadIdx.x;
  int ic = tid >> 1, wseg = (tid & 1) * 8;
  uint4 v = *(const uint4*)(src + (size_t)(b*CC + ic)*HWSZ + h*256 + w0 + wseg);
  u16 tmp[8]; *(uint4*)tmp = v;
  #pragma unroll
  for (int k = 0; k < 8; ++k) t[wseg + k][ic] = tmp[k];
  __syncthreads();
  int w = tid >> 4, part = (tid & 15) * 8;
  uint4 o = *(const uint4*)&t[w][part];
  *(uint4*)(dst + ((size_t)(b*256 + h)*256 + (w0 + w))*128 + part) = o;
}

// ---------------- MFMA implicit-GEMM conv, per-tap staging via global_load_lds ----------------
// 13 phases (row-OOB taps skipped: exact zeros). Staging: async global->LDS 16B/lane,
// linear LDS [128][128] with XOR swizzle applied to the per-lane GLOBAL source
// (c16' = c16 ^ (px&7)) and the same involution on the ds_read side -> <=2-way conflicts.
__launch_bounds__(256)
__global__ void k_conv5g(const u16* __restrict__ xcl, const u16* __restrict__ Kwb,
                         const float* __restrict__ biasK, const u16* __restrict__ zp,
                         u16* __restrict__ outp){
  __shared__ u16 As[128*128];
  __shared__ u16 Bs[128*128];
  int tid = threadIdx.x;
  int wv = tid >> 6, lane = tid & 63;
  int q = lane >> 4, l16 = lane & 15;
  int pt0 = blockIdx.x;
  int pt = (pt0 & 7) * 128 + (pt0 >> 3);   // XCD-chunked swizzle (1024 % 8 == 0)
  int b = pt >> 9, h = (pt >> 1) & 255, w0 = (pt & 1) << 7;
  int mrow = (wv & 1) << 6, nrow = (wv >> 1) << 6;
  const u16* xb_b = xcl + (size_t)b*HWSZ*128;
  f32x4 acc[4][4];
  #pragma unroll
  for (int mt = 0; mt < 4; ++mt)
    #pragma unroll
    for (int nt = 0; nt < 4; ++nt) acc[mt][nt] = (f32x4){0.f,0.f,0.f,0.f};

  // per-thread staging constants: seg = i*256 + tid -> px = seg>>4, c16p = seg&15
  int px_t   = tid >> 4;            // px for i=0; i adds 16 per step
  int c16p_t = tid & 15;
  int swzread = (l16 & 7) << 3;     // read-side XOR operand in u16 units (per 8-elem chunk)

  for (int t = 0; t < 13; ++t){
    int di = c_DI[t], dj = c_DJ[t];
    int hh2 = h + di;
    if ((unsigned)hh2 >= 256u) continue;   // whole tap contributes zero -> skip (block-uniform)
    const u16* rowbase = xb_b + (size_t)hh2*32768;
    const u16* Bb = Kwb + t*16384;
    __syncthreads();                 // prior phase's LDS reads complete
    #pragma unroll
    for (int i = 0; i < 8; ++i){
      int px   = px_t + i*16;
      int c16s = c16p_t ^ (px & 7);
      int col  = w0 + dj + px;
      const u16* asrc = ((unsigned)col < 256u) ? (rowbase + col*128 + c16s*8) : zp;
      const u16* bsrc = Bb + px*128 + c16s*8;
      u16* albase = &As[(i*256 + wv*64) * 8];   // wave-uniform LDS base
      u16* blbase = &Bs[(i*256 + wv*64) * 8];
      gload16(asrc, albase);
      gload16(bsrc, blbase);
    }
    __syncthreads();                 // vmcnt(0) drain: staged data visible
    #pragma unroll
    for (int kc = 0; kc < 4; ++kc){
      int swz = ((kc*4 + q) << 3) ^ swzread;   // ((kc*4+q) ^ (r&7))*8, r&7 == l16&7
      short8 af[4], bf[4];
      #pragma unroll
      for (int mt = 0; mt < 4; ++mt)
        af[mt] = *(const short8*)&As[(mrow + mt*16 + l16)*128 + swz];
      #pragma unroll
      for (int nt = 0; nt < 4; ++nt)
        bf[nt] = *(const short8*)&Bs[(nrow + nt*16 + l16)*128 + swz];
      #pragma unroll
      for (int mt = 0; mt < 4; ++mt)
        #pragma unroll
        for (int nt = 0; nt < 4; ++nt)
          acc[mt][nt] = __builtin_amdgcn_mfma_f32_16x16x32_bf16(af[mt], bf[nt], acc[mt][nt], 0, 0, 0);
    }
  }
  #pragma unroll
  for (int nt = 0; nt < 4; ++nt){
    int n = nrow + nt*16 + l16;
    float bv = biasK[n];
    size_t cbase = (size_t)(b*CC + n)*HWSZ + h*256 + w0;
    #pragma unroll
    for (int mt = 0; mt < 4; ++mt){
      int m = mrow + mt*16 + q*4;
      ushort4 st;
      st.x = f2b(acc[mt][nt][0] + bv);
      st.y = f2b(acc[mt][nt][1] + bv);
      st.z = f2b(acc[mt][nt][2] + bv);
      st.w = f2b(acc[mt][nt][3] + bv);
      *(ushort4*)(outp + cbase + m) = st;
    }
  }
}

// ---------------- MFMA 1x1 GEMM: out[px][oc] = X_cl[px][:]·W[oc][:] ----------------
// mode 0: window layout [b][hh][ww][sel][head][pos][d] (qkv, nsel=3)
// mode 1: plane CF [b][oc][HW]; f32 if (Yf && *flag)   (proj_pw, nsel=1)
__launch_bounds__(256)
__global__ void k_mgemm(const u16* __restrict__ Xcl, const u16* __restrict__ W,
                        u16* __restrict__ Y, float* __restrict__ Yf,
                        const int* __restrict__ flag, int nsel, int mode){
  __shared__ u16 As[128][136];
  __shared__ u16 Bs[128][136];   // reused as Cs[m][n] in mode-0 epilogue
  int tid = threadIdx.x;
  int wv = tid >> 6, lane = tid & 63;
  int q = lane >> 4, l16 = lane & 15;
  int pt = blockIdx.x;
  int b = pt >> 9, h = (pt >> 1) & 255, w0 = (pt & 1) << 7;
  int mrow = (wv & 1) << 6, nrow = (wv >> 1) << 6;
  const u16* Abase = Xcl + ((size_t)(b*256 + h)*256 + w0)*128;
  #pragma unroll
  for (int i = 0; i < 8; ++i){
    int seg = i*256 + tid;
    *(uint4*)&As[seg >> 4][(seg & 15) << 3] = *(const uint4*)(Abase + seg*8);
  }
  for (int sel = 0; sel < nsel; ++sel){
    __syncthreads();                  // Bs/Cs free of previous readers
    const u16* Wb = W + sel*16384;
    #pragma unroll
    for (int i = 0; i < 8; ++i){
      int seg = i*256 + tid;
      *(uint4*)&Bs[seg >> 4][(seg & 15) << 3] = *(const uint4*)(Wb + seg*8);
    }
    __syncthreads();
    f32x4 acc[4][4];
    #pragma unroll
    for (int mt = 0; mt < 4; ++mt)
      #pragma unroll
      for (int nt = 0; nt < 4; ++nt) acc[mt][nt] = (f32x4){0.f,0.f,0.f,0.f};
    #pragma unroll
    for (int kc = 0; kc < 4; ++kc){
      short8 af[4], bf[4];
      #pragma unroll
      for (int mt = 0; mt < 4; ++mt) af[mt] = *(const short8*)&As[mrow + mt*16 + l16][kc*32 + q*8];
      #pragma unroll
      for (int nt = 0; nt < 4; ++nt) bf[nt] = *(const short8*)&Bs[nrow + nt*16 + l16][kc*32 + q*8];
      #pragma unroll
      for (int mt = 0; mt < 4; ++mt)
        #pragma unroll
        for (int nt = 0; nt < 4; ++nt)
          acc[mt][nt] = __builtin_amdgcn_mfma_f32_16x16x32_bf16(af[mt], bf[nt], acc[mt][nt], 0, 0, 0);
    }
    if (mode == 0){
      __syncthreads();                // all waves done with Bs
      #pragma unroll
      for (int mt = 0; mt < 4; ++mt){
        int m0i = mrow + mt*16 + q*4;
        #pragma unroll
        for (int nt = 0; nt < 4; ++nt){
          int n = nrow + nt*16 + l16;
          Bs[m0i+0][n] = f2b(acc[mt][nt][0]);
          Bs[m0i+1][n] = f2b(acc[mt][nt][1]);
          Bs[m0i+2][n] = f2b(acc[mt][nt][2]);
          Bs[m0i+3][n] = f2b(acc[mt][nt][3]);
        }
      }
      __syncthreads();
      int win = tid >> 4, head = tid & 15;
      size_t obase = (((((size_t)b*32 + (h >> 3))*32 + (w0 >> 3) + win)*3 + sel)*16 + head)*512
                     + (size_t)(h & 7)*64;
      #pragma unroll
      for (int pj = 0; pj < 8; ++pj){
        uint4 vv = *(const uint4*)&Bs[win*8 + pj][head*8];
        *(uint4*)(Y + obase + pj*8) = vv;
      }
    } else {
      int f32o = (Yf != nullptr) && (*flag != 0);
      #pragma unroll
      for (int nt = 0; nt < 4; ++nt){
        int n = nrow + nt*16 + l16;
        size_t cbase = (size_t)(b*CC + n)*HWSZ + h*256 + w0;
        #pragma unroll
        for (int mt = 0; mt < 4; ++mt){
          int m = mrow + mt*16 + q*4;
          if (f32o){
            float4 st; st.x=acc[mt][nt][0]; st.y=acc[mt][nt][1];
            st.z=acc[mt][nt][2]; st.w=acc[mt][nt][3];
            *(float4*)(Yf + cbase + m) = st;
          } else {
            ushort4 st;
            st.x = f2b(acc[mt][nt][0]); st.y = f2b(acc[mt][nt][1]);
            st.z = f2b(acc[mt][nt][2]); st.w = f2b(acc[mt][nt][3]);
            *(ushort4*)(Y + cbase + m) = st;
          }
        }
      }
    }
  }
}

// ---------------- windowed attention v3: one wave per (window, head) ----------------
// qkvw layout: [b][hh][ww][sel(3)][head(16)][pos(64)][d(8)] bf16
// grid: (8 window-groups, 32 hh, b*16+head); block 256 = 4 waves = 4 windows
__launch_bounds__(256)
__global__ void k_attn3(const u16* __restrict__ qkvw, const float* __restrict__ relo,
                        u16* __restrict__ obuf){
  __shared__ float relf[228];
  __shared__ u16  kls[4][64][8];
  __shared__ float vls[4][64][8];
  int tid = threadIdx.x, wv = tid >> 6, lane = tid & 63;
  int b = blockIdx.z >> 4, head = blockIdx.z & 15;
  int hh = blockIdx.y, ww = blockIdx.x * 4 + wv;

  for (int e = tid; e < 225; e += 256) relf[e] = relo[head*225 + e];

  size_t base = (((size_t)b*32 + hh)*32 + ww)*3*8192 + (size_t)head*512;
  uint4 qv = *(const uint4*)(qkvw + base + lane*8);
  *(uint4*)&kls[wv][lane][0] = *(const uint4*)(qkvw + base + 8192 + lane*8);
  {
    uint4 raw = *(const uint4*)(qkvw + base + 16384 + lane*8);
    u16 tv[8]; *(uint4*)tv = raw;
    float4 lo, hi;
    lo.x=b2f(tv[0]); lo.y=b2f(tv[1]); lo.z=b2f(tv[2]); lo.w=b2f(tv[3]);
    hi.x=b2f(tv[4]); hi.y=b2f(tv[5]); hi.z=b2f(tv[6]); hi.w=b2f(tv[7]);
    *(float4*)&vls[wv][lane][0] = lo;
    *(float4*)&vls[wv][lane][4] = hi;
  }
  __syncthreads();     // relf visibility across waves (K/V slices are same-wave)

  int qi = lane >> 3, qj = lane & 7;
  const float* rbase = relf + (qi + 7)*15 + (qj + 7);
  float s[64];
#if HAVE_DOT2
  typedef __bf16 bf2 __attribute__((ext_vector_type(2)));
  bf2 q0 = __builtin_bit_cast(bf2, qv.x), q1 = __builtin_bit_cast(bf2, qv.y);
  bf2 q2 = __builtin_bit_cast(bf2, qv.z), q3 = __builtin_bit_cast(bf2, qv.w);
  #pragma unroll
  for (int kp = 0; kp < 64; ++kp){
    uint4 kv = *(const uint4*)&kls[wv][kp][0];
    float d = __builtin_amdgcn_fdot2_f32_bf16(q3, __builtin_bit_cast(bf2, kv.w), 0.f, false);
    d = __builtin_amdgcn_fdot2_f32_bf16(q2, __builtin_bit_cast(bf2, kv.z), d, false);
    d = __builtin_amdgcn_fdot2_f32_bf16(q1, __builtin_bit_cast(bf2, kv.y), d, false);
    d = __builtin_amdgcn_fdot2_f32_bf16(q0, __builtin_bit_cast(bf2, kv.x), d, false);
    s[kp] = fmaf(d, ATT_SCALE, rbase[-((kp>>3)*15 + (kp&7))]);
  }
#else
  float qf[8];
  { u16 tq[8]; *(uint4*)tq = qv;
    #pragma unroll
    for (int d = 0; d < 8; ++d) qf[d] = b2f(tq[d]); }
  #pragma unroll
  for (int kp = 0; kp < 64; ++kp){
    uint4 kv = *(const uint4*)&kls[wv][kp][0];
    u16 tk[8]; *(uint4*)tk = kv;
    float d = 0.f;
    #pragma unroll
    for (int dd = 0; dd < 8; ++dd) d = fmaf(qf[dd], b2f(tk[dd]), d);
    s[kp] = fmaf(d, ATT_SCALE, rbase[-((kp>>3)*15 + (kp&7))]);
  }
#endif
  float t16[16];
  #pragma unroll
  for (int i = 0; i < 16; ++i)
    t16[i] = fmaxf(fmaxf(s[i], s[i+16]), fmaxf(s[i+32], s[i+48]));
  float mx = t16[0];
  #pragma unroll
  for (int i = 1; i < 16; ++i) mx = fmaxf(mx, t16[i]);
  #pragma unroll
  for (int kp = 0; kp < 64; ++kp) s[kp] = __expf(s[kp] - mx);
  #pragma unroll
  for (int i = 0; i < 16; ++i)
    t16[i] = (s[i] + s[i+16]) + (s[i+32] + s[i+48]);
  float sum = t16[0];
  #pragma unroll
  for (int i = 1; i < 16; ++i) sum += t16[i];
  float inv = 1.0f / sum;
  float ov[8] = {0.f,0.f,0.f,0.f,0.f,0.f,0.f,0.f};
  #pragma unroll
  for (int kp = 0; kp < 64; ++kp){
    float4 va = *(const float4*)&vls[wv][kp][0];
    float4 vb = *(const float4*)&vls[wv][kp][4];
    float pp = s[kp];
    ov[0] = fmaf(pp, va.x, ov[0]); ov[1] = fmaf(pp, va.y, ov[1]);
    ov[2] = fmaf(pp, va.z, ov[2]); ov[3] = fmaf(pp, va.w, ov[3]);
    ov[4] = fmaf(pp, vb.x, ov[4]); ov[5] = fmaf(pp, vb.y, ov[5]);
    ov[6] = fmaf(pp, vb.z, ov[6]); ov[7] = fmaf(pp, vb.w, ov[7]);
  }
  size_t obase = (size_t)(b*CC + head*8)*HWSZ + (size_t)(hh*8 + qi)*256 + ww*8 + qj;
  #pragma unroll
  for (int d = 0; d < 8; ++d)
    obuf[obase + (size_t)d*HWSZ] = f2b(ov[d] * inv);
}

// ---------------- u = avgpool_x(o) + avgpool_y(o) + local (LDS-tiled) ----------------
// 64x64 output tile per block; halo tile 71 rows x 80 cols (cols w0-8 .. w0+71)
__launch_bounds__(256)
__global__ void k_pool2(const u16* __restrict__ obuf, u16* __restrict__ localb){
  __shared__ u16 t[71][88];       // row pad to 88 u16 (176B) keeps uint4 alignment
  int bc = blockIdx.z;
  int h0 = blockIdx.y * 64, w0 = blockIdx.x * 64;
  int tid = threadIdx.x;
  const u16* op = obuf + (size_t)bc * HWSZ;

  // load 71 rows x 10 ushort8-chunks: rows h0-3..h0+67, cols w0-8..w0+71
  for (int e = tid; e < 710; e += 256){
    int tr = e / 10, ci = e - tr*10;
    int gt = h0 - 3 + tr;
    if (gt == 256) gt = 254;               // reflect pad row
    bool rv = (unsigned)gt <= 255u;        // else zero (reduce_window pad)
    int g0 = w0 - 8 + ci*8;
    uint4 v = {0,0,0,0};
    if (rv){
      if (g0 >= 0 && g0 <= 248){
        v = *(const uint4*)(op + gt*256 + g0);
      } else {
        u16 tmp[8];
        #pragma unroll
        for (int j = 0; j < 8; ++j){
          int g = g0 + j;
          if (g == 256) g = 254;           // reflect pad col
          tmp[j] = ((unsigned)g <= 255u) ? op[gt*256 + g] : (u16)0;
        }
        v = *(const uint4*)tmp;
      }
    }
    *(uint4*)&t[tr][ci*8] = v;
  }
  __syncthreads();

  int ty = tid >> 4, tx = tid & 15;
  int r0 = ty*4, c0 = tx*4;                // 4x4 outputs per thread
  // vertical 8-tap sums via sliding window: sxv[r][c] = sum_{i=0..7} t[r0+r+i][c0+8+c]
  float sxv[4][4];
  #pragma unroll
  for (int c = 0; c < 4; ++c){
    float col[11];
    #pragma unroll
    for (int i = 0; i < 11; ++i) col[i] = b2f(t[r0+i][c0+8+c]);
    float s = ((col[0]+col[1])+(col[2]+col[3]))+((col[4]+col[5])+(col[6]+col[7]));
    sxv[0][c] = s;
    s += col[8]  - col[0]; sxv[1][c] = s;
    s += col[9]  - col[1]; sxv[2][c] = s;
    s += col[10] - col[2]; sxv[3][c] = s;
  }
  #pragma unroll
  for (int r = 0; r < 4; ++r){
    int rr = r0 + r;
    // horizontal 8-tap sums: sy[c] = sum_{j=0..7} t[rr+3][c0+5+c+j]
    float pre[11];
    #pragma unroll
    for (int j = 0; j < 11; ++j) pre[j] = b2f(t[rr+3][c0+5+j]);
    float sy0 = ((pre[0]+pre[1])+(pre[2]+pre[3]))+((pre[4]+pre[5])+(pre[6]+pre[7]));
    float sy1 = sy0 + pre[8]  - pre[0];
    float sy2 = sy1 + pre[9]  - pre[1];
    float sy3 = sy2 + pre[10] - pre[2];
    size_t base = (size_t)bc*HWSZ + (size_t)(h0+rr)*256 + (w0+c0);
    ushort4 lv = *(const ushort4*)(localb + base);
    ushort4 st;
    st.x = f2b((sxv[r][0]+sy0)*0.125f + b2f(lv.x));
    st.y = f2b((sxv[r][1]+sy1)*0.125f + b2f(lv.y));
    st.z = f2b((sxv[r][2]+sy2)*0.125f + b2f(lv.z));
    st.w = f2b((sxv[r][3]+sy3)*0.125f + b2f(lv.w));
    *(ushort4*)(localb + base) = st;
  }
}

// ---------------- depthwise 8x8 conv + bn (CF in, CF out), LDS-tiled ----------------
// 64x128 output tile per block; halo 71 rows x 144 cols bf16 in LDS.
// Each thread: 4 rows x 8 cols outputs; 11 tap rows shared; fdot2 bf16 inner product.
__launch_bounds__(256)
__global__ void k_dw2(const u16* __restrict__ u_, const u16* __restrict__ dww,
                      const u16* __restrict__ g, const u16* __restrict__ bta,
                      u16* __restrict__ dwout){
  __shared__ u16 xt[71][152];     // row stride 304 B (16B-aligned)
  int c = blockIdx.z & 127, b = blockIdx.z >> 7;
  int h0 = blockIdx.y * 64, w0 = blockIdx.x * 128;
  int tid = threadIdx.x;
  const u16* up = u_ + (size_t)(b*CC + c)*HWSZ;

  // halo: LDS row tr -> global row h0-3+tr; LDS col l -> global col w0-8+l (l<144)
  for (int e = tid; e < 71*18; e += 256){
    int tr = e / 18, ci = e - tr*18;
    int gt = h0 - 3 + tr;
    if (gt == 256) gt = 254;               // reflect row (pad-1 frame)
    int g0 = w0 - 8 + ci*8;
    uint4 v = {0,0,0,0};
    if ((unsigned)gt <= 255u){
      if (g0 >= 0 && g0 <= 248){
        v = *(const uint4*)(up + gt*256 + g0);
      } else {
        u16 tmp[8];
        #pragma unroll
        for (int j = 0; j < 8; ++j){
          int gw = g0 + j;
          if (gw == 256) gw = 254;         // reflect col
          tmp[j] = ((unsigned)gw <= 255u) ? up[gt*256 + gw] : (u16)0;
        }
        v = *(const uint4*)tmp;
      }
    }
    *(uint4*)&xt[tr][ci*8] = v;
  }

#if HAVE_DOT2
  typedef __bf16 bf2v __attribute__((ext_vector_type(2)));
  // weights as raw bf16 pairs: wp[wr*4+p] = (w[wr][2p], w[wr][2p+1])
  unsigned int wp[32];
  {
    const uint4* wsrc = (const uint4*)(dww + c*64);
    #pragma unroll
    for (int t = 0; t < 8; ++t){
      uint4 v = wsrc[t];
      wp[t*4+0]=v.x; wp[t*4+1]=v.y; wp[t*4+2]=v.z; wp[t*4+3]=v.w;
    }
  }
#else
  float wf[64];
  {
    const u16* wsrc = dww + c*64;
    #pragma unroll
    for (int t = 0; t < 64; ++t) wf[t] = b2f(wsrc[t]);
  }
#endif
  __syncthreads();

  int tx = tid & 15, ty = tid >> 4;
  int r0 = ty*4;                  // tile-local output rows r0..r0+3
  int cb = tx*8;                  // output col c -> LDS col cb+8+k; taps cols cb+5+k+j
  float acc[4][8];
  #pragma unroll
  for (int r = 0; r < 4; ++r)
    #pragma unroll
    for (int k = 0; k < 8; ++k) acc[r][k] = 0.f;

  #pragma unroll
  for (int i = 0; i < 11; ++i){
    const u16* rowp = &xt[r0 + i][cb + 4];
    uint2 av = *(const uint2*)(rowp);       // cols +4..+7
    uint4 mv = *(const uint4*)(rowp + 4);   // cols +8..+15
    uint2 zv = *(const uint2*)(rowp + 12);  // cols +16..+19
    unsigned int d0=av.x, d1=av.y, d2=mv.x, d3=mv.y, d4=mv.z, d5=mv.w, d6=zv.x, d7=zv.y;
    unsigned int dd[8] = {d0,d1,d2,d3,d4,d5,d6,d7};
#if HAVE_DOT2
    // xp[t] = bf16 pair (col 4+t, col 5+t), t=1..14
    unsigned int xp[15];
    #pragma unroll
    for (int t = 1; t < 15; ++t)
      xp[t] = (t & 1) ? ((dd[t>>1] >> 16) | (dd[(t>>1)+1] << 16)) : dd[t>>1];
    #pragma unroll
    for (int dr = 0; dr < 4; ++dr){
      int wr = i - dr;
      if (wr >= 0 && wr < 8){
        #pragma unroll
        for (int k = 0; k < 8; ++k){
          float s = acc[dr][k];
          #pragma unroll
          for (int p = 0; p < 4; ++p)
            s = __builtin_amdgcn_fdot2_f32_bf16(
                  __builtin_bit_cast(bf2v, wp[wr*4+p]),
                  __builtin_bit_cast(bf2v, xp[1+k+2*p]), s, false);
          acc[dr][k] = s;
        }
      }
    }
#else
    float xw[16];
    #pragma unroll
    for (int t = 1; t < 16; ++t){
      unsigned int w32 = dd[t>>1];
      xw[t] = __uint_as_float((t & 1) ? (w32 & 0xFFFF0000u) : (w32 << 16));
    }
    #pragma unroll
    for (int dr = 0; dr < 4; ++dr){
      int wr = i - dr;
      if (wr >= 0 && wr < 8){
        #pragma unroll
        for (int k = 0; k < 8; ++k){
          float s = acc[dr][k];
          #pragma unroll
          for (int j = 0; j < 8; ++j)
            s = fmaf(wf[wr*8+j], xw[1+k+j], s);
          acc[dr][k] = s;
        }
      }
    }
#endif
  }

  float scale = b2f(g[c]) * RSQE;
  float bb = b2f(bta[c]);
  size_t obase = (size_t)(b*CC + c)*HWSZ + (size_t)(h0 + r0)*256 + w0 + cb;
  #pragma unroll
  for (int r = 0; r < 4; ++r){
    u16 po[8];
    #pragma unroll
    for (int k = 0; k < 8; ++k) po[k] = f2b(acc[r][k]*scale + bb);
    *(uint4*)(dwout + obase + (size_t)r*256) = *(uint4*)po;
  }
}

// ---------------- launcher ----------------
extern "C" void kernel_launch(void* const* d_in, const int* in_sizes, int n_in,
                              void* d_out, int out_size, void* d_ws, size_t ws_size,
                              hipStream_t stream) {
  char* p = (char*)d_ws;
  u16* cx     = (u16*)p; p += 33554432;   // canonical CF x -> attn output planes
  u16* xcl    = (u16*)p; p += 33554432;   // scaled CL x -> dw output CL
  u16* qkvb   = (u16*)p; p += 100663296;  // qkvw window layout -> dw output CF
  u16* cw     = (u16*)p; p += 1074176;
  float* A_h    = (float*)p; p += 65536;
  float* A_w    = (float*)p; p += 65536;
  u16*  Kwb     = (u16*)p;  p += 425984;
  float* biasK  = (float*)p; p += 1024;
  float* mh     = (float*)p; p += 262144;
  float* mw     = (float*)p; p += 262144;
  float* s_h    = (float*)p; p += 262144;
  float* s_w    = (float*)p; p += 262144;
  int* flag     = (int*)p;   p += 256;
  float* relo   = (float*)p; p += 16384;  // rel table head-major f32 [16][225]
  u16* zpage    = (u16*)p;   p += 4096;   // zeroed page for conv halo source

  u16* localb = (u16*)d_out;     // d_out doubles as `local` scratch until final GEMM
  u16* qkvw   = qkvb;
  u16* obuf   = cx;              // attn output planes (cx dead after qkv gemm)
  u16* dwbuf  = qkvb;            // dw CF output (qkvw dead after attn)
  u16* dwcl   = xcl;             // dw CL output (xcl dead after qkv gemm)

  const int O_h1=0, O_w1=16384, O_fh=32768, O_fw=49152, O_l1w=65536, O_l1g=212992,
            O_l1b=213120, O_l2w=213248, O_l2g=229632, O_l2b=229760, O_hge=229888,
            O_fcw=377344, O_fcb=459264, O_qkvw=459392, O_rel=508544, O_dw=512144,
            O_pg=520336, O_pb=520464, O_pw=520592;

  k_detect<<<1, 256, 0, stream>>>((const u16*)d_in[0], flag);
  k_zero<<<1, 256, 0, stream>>>((uint4*)zpage);
  k_ingest4<<<16384, 256, 0, stream>>>(d_in[0], cx, 4194304, flag);
  PtrL pl;
  for (int i = 0; i < 19; ++i) pl.p[i] = d_in[i+1];
  k_ingest_w<<<525, 256, 0, stream>>>(pl, cw, flag);

  k_prep_A<<<64, 256, 0, stream>>>(cw+O_fh, cw+O_h1, cw+O_fw, cw+O_w1,
                                   cw+O_l1b, cw+O_l2b, cw+O_fcb, A_h, A_w, biasK);
  k_prep_rel<<<15, 256, 0, stream>>>(cw+O_rel, relo);
  k_prep_K<<<64, 256, 0, stream>>>(cw+O_hge, cw+O_fcw, cw+O_l1w, cw+O_l1g,
                                   cw+O_l2w, cw+O_l2g, Kwb);
  k_means<<<dim3(128, 2), 256, 0, stream>>>(cx, mh, mw);
  k_sig<<<dim3(128, 2, 2), 256, 0, stream>>>(A_h, A_w, mh, mw, s_h, s_w);
  k_scale2cl<<<dim3(16, 1, 512), 256, 0, stream>>>(cx, s_h, s_w, xcl);

  k_conv5g<<<1024, 256, 0, stream>>>(xcl, Kwb, biasK, zpage, localb);
  k_mgemm<<<1024, 256, 0, stream>>>(xcl, cw+O_qkvw, qkvw, nullptr, flag, 3, 0);
  k_attn3<<<dim3(8, 32, 32), 256, 0, stream>>>(qkvw, relo, obuf);
  k_pool2<<<dim3(4, 4, 256), 256, 0, stream>>>(obuf, localb);
  k_dw2<<<dim3(2, 4, 256), 256, 0, stream>>>(localb, cw+O_dw, cw+O_pg, cw+O_pb, dwbuf);
  k_cf2cl<<<dim3(16, 1, 512), 256, 0, stream>>>(dwbuf, dwcl);
  k_mgemm<<<1024, 256, 0, stream>>>(dwcl, cw+O_pw, (u16*)d_out, (float*)d_out, flag, 1, 1);
}